// Round 9
// baseline (249.865 us; speedup 1.0000x reference)
//
#include <hip/hip_runtime.h>

typedef __attribute__((ext_vector_type(8))) short short8v;
typedef __attribute__((ext_vector_type(4))) float f32x4;

// ---------------- workspace layout ----------------
// ws[0 .. 10239] (floats) = bf16 fragment table for 5 matrices (40960 B):
//   shorts idx = ((m*2+kt)*4+ct)*512 + lane*8 + jj
//   holds M_m[k = kt*32 + sigma(lane,jj)][c = ct*16 + (lane&15)]
// m: 0=A_qk(WqWk^T) 1=G_q(WqWq^T) 2=G_k 3=G_v 4=M_vo(Wv@Wo)
#define WS_PQ  20480   // Wq@bk [64]
#define WS_PK  20544   // Wk@bq [64]
#define WS_UQ  20608   // Wq@bq
#define WS_UK  20672   // Wk@bk
#define WS_UV  20736   // Wv@bv
#define WS_RVO 20800   // bv@Wo [64]
#define WS_SC  20864   // c0=bq.bk, |bq|^2, |bk|^2, |bv|^2
#define WS_PE  20992   // pe[16][64]

#define RPX    4640    // per-pixel LDS region bytes (290*16, de-aliased vs 128)
#define PT_OFF 2064    // P-tilde A-frags (32 lanes * 16B)
#define YT_OFF 2576    // Yv B-frags (4 ct * 32 lanes * 16B)
#define NRM_OFF (8*RPX)

__device__ __forceinline__ unsigned short f2bf(float f) {
  unsigned u = __float_as_uint(f);
  u += 0x7fffu + ((u >> 16) & 1u);          // RNE
  return (unsigned short)(u >> 16);
}
__device__ __forceinline__ float bf2f(unsigned short h) {
  return __uint_as_float(((unsigned)h) << 16);
}
__device__ __forceinline__ f32x4 mfma16(short8v a, short8v b, f32x4 c) {
  return __builtin_amdgcn_mfma_f32_16x16x32_bf16(a, b, c, 0, 0, 0);
}

// ---- DPP 16-lane reduces (VALU-only; replaces ds_bpermute shuffle ladders) ----
// dpp_ctrl must be a compile-time constant -> template parameter.
// row_ror:8 = 0x128, row_ror:4 = 0x124, quad_perm xor2 = 0x4E, xor1 = 0xB1
template<int CTRL>
__device__ __forceinline__ float dpp_mov(float v) {
  return __uint_as_float((unsigned)__builtin_amdgcn_update_dpp(
      0, (int)__float_as_uint(v), CTRL, 0xF, 0xF, true));
}
__device__ __forceinline__ float row_sum16(float v) {
  v += dpp_mov<0x128>(v);
  v += dpp_mov<0x124>(v);
  v += dpp_mov<0x4E>(v);
  v += dpp_mov<0xB1>(v);
  return v;
}
__device__ __forceinline__ float row_max16(float v) {
  v = fmaxf(v, dpp_mov<0x128>(v));
  v = fmaxf(v, dpp_mov<0x124>(v));
  v = fmaxf(v, dpp_mov<0x4E>(v));
  v = fmaxf(v, dpp_mov<0xB1>(v));
  return v;
}

// ---------------- K1: fully wave-parallel precompute ----------------
__global__ __launch_bounds__(256) void k1(
    const float* __restrict__ Wq, const float* __restrict__ bq,
    const float* __restrict__ Wk, const float* __restrict__ bk,
    const float* __restrict__ Wv, const float* __restrict__ bv,
    const float* __restrict__ Wo, float* __restrict__ ws)
{
  const int lane = threadIdx.x & 63;
  const int wid  = (blockIdx.x << 2) | (threadIdx.x >> 6);
  unsigned short* wsu = (unsigned short*)ws;

  if (wid < 320) {  // M_m[a][c=lane] = dot over d=0..511
    const int m = wid >> 6, a = wid & 63;
    float a0 = 0.f, a1 = 0.f, a2 = 0.f, a3 = 0.f;
    if (m < 4) {
      const float* L = (m <= 1) ? Wq : (m == 2) ? Wk : Wv;
      const float* R = (m == 1) ? Wq : (m == 3) ? Wv : Wk;  // m0,m2 -> Wk
      const float* Lr = L + a * 512;
      const float* Rr = R + lane * 512;
#pragma unroll 4
      for (int d = 0; d < 512; d += 4) {
        const float4 l4 = *(const float4*)(Lr + d);
        const float4 r4 = *(const float4*)(Rr + d);
        a0 = fmaf(l4.x, r4.x, a0); a1 = fmaf(l4.y, r4.y, a1);
        a2 = fmaf(l4.z, r4.z, a2); a3 = fmaf(l4.w, r4.w, a3);
      }
    } else {        // M_vo[a][c] = sum_d Wv[a][d] * Wo[d][c], coalesced Wo
      const float* Lr = Wv + a * 512;
#pragma unroll 4
      for (int d = 0; d < 512; d += 4) {
        const float4 l4 = *(const float4*)(Lr + d);
        a0 = fmaf(l4.x, Wo[(d + 0) * 64 + lane], a0);
        a1 = fmaf(l4.y, Wo[(d + 1) * 64 + lane], a1);
        a2 = fmaf(l4.z, Wo[(d + 2) * 64 + lane], a2);
        a3 = fmaf(l4.w, Wo[(d + 3) * 64 + lane], a3);
      }
    }
    const float p = (a0 + a1) + (a2 + a3);
    const int c = lane;
    wsu[((m * 2 + (a >> 5)) * 4 + (c >> 4)) * 512
        + (((a >> 3) & 3) * 16 + (c & 15)) * 8 + (a & 7)] = f2bf(p);
    return;
  }

  if (wid < 325) {  // vectors: out[a=lane] = dot(L_row(a), r)
    const int v = wid - 320;
    const float* L = (v == 0 || v == 2) ? Wq : (v == 1 || v == 3) ? Wk : Wv;
    const float* r = (v == 0 || v == 3) ? bk : (v == 1 || v == 2) ? bq : bv;
    const int dst = (v == 0) ? WS_PQ : (v == 1) ? WS_PK : (v == 2) ? WS_UQ
                  : (v == 3) ? WS_UK : WS_UV;
    const float* Lr = L + lane * 512;
    float a0 = 0.f, a1 = 0.f, a2 = 0.f, a3 = 0.f;
#pragma unroll 4
    for (int d = 0; d < 512; d += 4) {
      const float4 l4 = *(const float4*)(Lr + d);
      const float4 r4 = *(const float4*)(r + d);
      a0 = fmaf(l4.x, r4.x, a0); a1 = fmaf(l4.y, r4.y, a1);
      a2 = fmaf(l4.z, r4.z, a2); a3 = fmaf(l4.w, r4.w, a3);
    }
    ws[dst + lane] = (a0 + a1) + (a2 + a3);
    return;
  }

  if (wid == 325) {  // rvo[c=lane] = sum_d bv[d] * Wo[d][c]
    float a0 = 0.f, a1 = 0.f, a2 = 0.f, a3 = 0.f;
#pragma unroll 4
    for (int d = 0; d < 512; d += 4) {
      const float4 b4 = *(const float4*)(bv + d);
      a0 = fmaf(b4.x, Wo[(d + 0) * 64 + lane], a0);
      a1 = fmaf(b4.y, Wo[(d + 1) * 64 + lane], a1);
      a2 = fmaf(b4.z, Wo[(d + 2) * 64 + lane], a2);
      a3 = fmaf(b4.w, Wo[(d + 3) * 64 + lane], a3);
    }
    ws[WS_RVO + lane] = (a0 + a1) + (a2 + a3);
    return;
  }

  if (wid == 326) {  // scalars: c0=bq.bk, |bq|^2, |bk|^2, |bv|^2
#pragma unroll
    for (int s = 0; s < 4; ++s) {
      const float* u  = (s <= 1) ? bq : (s == 2) ? bk : bv;
      const float* vv = (s == 0 || s == 2) ? bk : (s == 1) ? bq : bv;
      float p = 0.f;
#pragma unroll
      for (int dd = 0; dd < 8; ++dd) p = fmaf(u[lane + dd * 64], vv[lane + dd * 64], p);
#pragma unroll
      for (int dd = 1; dd < 64; dd <<= 1) p += __shfl_xor(p, dd);
      if (lane == 0) ws[WS_SC + s] = p;
    }
    return;
  }

  if (wid == 327) {  // positional encoding
    for (int idx = lane; idx < 1024; idx += 64) {
      int f = idx >> 6, ch = idx & 63;
      float div = __expf(-(float)(ch & ~1) * 0.14391156510303f);  // ln(1e4)/64
      float arg = (float)f * div;
      ws[WS_PE + idx] = (ch & 1) ? cosf(arg) : sinf(arg);
    }
  }
}

// load 8 B-frags of matrix MM (global, L2-hot); 2 MFMAs into each col-tile
template<int MM>
__device__ __forceinline__ void product5(const unsigned short* wsu, int lane,
                                         short8v xa0, short8v xa1, f32x4 (&acc)[4]) {
  const short8v b00 = *(const short8v*)(wsu + ((MM * 2 + 0) * 4 + 0) * 512 + lane * 8);
  const short8v b01 = *(const short8v*)(wsu + ((MM * 2 + 0) * 4 + 1) * 512 + lane * 8);
  const short8v b02 = *(const short8v*)(wsu + ((MM * 2 + 0) * 4 + 2) * 512 + lane * 8);
  const short8v b03 = *(const short8v*)(wsu + ((MM * 2 + 0) * 4 + 3) * 512 + lane * 8);
  const short8v b10 = *(const short8v*)(wsu + ((MM * 2 + 1) * 4 + 0) * 512 + lane * 8);
  const short8v b11 = *(const short8v*)(wsu + ((MM * 2 + 1) * 4 + 1) * 512 + lane * 8);
  const short8v b12 = *(const short8v*)(wsu + ((MM * 2 + 1) * 4 + 2) * 512 + lane * 8);
  const short8v b13 = *(const short8v*)(wsu + ((MM * 2 + 1) * 4 + 3) * 512 + lane * 8);
  acc[0] = mfma16(xa0, b00, acc[0]);
  acc[1] = mfma16(xa0, b01, acc[1]);
  acc[2] = mfma16(xa0, b02, acc[2]);
  acc[3] = mfma16(xa0, b03, acc[3]);
  acc[0] = mfma16(xa1, b10, acc[0]);
  acc[1] = mfma16(xa1, b11, acc[1]);
  acc[2] = mfma16(xa1, b12, acc[2]);
  acc[3] = mfma16(xa1, b13, acc[3]);
}

// ---------------- K2: fused main kernel, 1 wave = 1 pixel ----------------
__global__ __launch_bounds__(512, 8) void k2_main(
    const float* __restrict__ x, const float* __restrict__ ws,
    const float* __restrict__ bo_g, float* __restrict__ out)
{
  __shared__ uint4 lds4[2384];   // 8*RPX + 8*32*4 = 38144 B
  char* lds = (char*)lds4;

  const int t = threadIdx.x;
  const int bid = blockIdx.x;
  // XCD-pair swizzle: blocks sharing a 64B input line land on the same XCD
  const int pb = (bid & ~15) | (((bid & 7) << 1) | ((bid >> 3) & 1));
  const int n0 = pb * 8;
  const size_t gbase = (size_t)(n0 >> 12) * 4194304 + (n0 & 4095);
  const unsigned short* wsu = (const unsigned short*)ws;

  {  // cooperative stage: xs = x + pe -> bf16 A-fragment-packed LDS
    const int px = t & 7, cc = t >> 3;
    const float* xb = x + gbase + px;
    char* wb = lds + px * RPX + (cc >> 5) * 1024 + (((cc >> 3) & 3) * 16) * 16 + (cc & 7) * 2;
#pragma unroll
    for (int f = 0; f < 16; ++f) {
      float v = xb[(size_t)(f * 64 + cc) * 4096] + ws[WS_PE + f * 64 + cc];
      *(unsigned short*)(wb + f * 16) = f2bf(v);
    }
  }
  __syncthreads();

  const int w = t >> 6, lane = t & 63, g = lane >> 4, lc = lane & 15;
  char* P = lds + w * RPX;
  float* nrmW = (float*)(lds + NRM_OFF) + w * 32;

  // xs A-fragments (also reused as B-operand for the score MFMA)
  const short8v xa0 = *(const short8v*)(P + lane * 16);
  const short8v xa1 = *(const short8v*)(P + 1024 + lane * 16);

  // per-lane xs values at this lane's D-layout positions (i=4g+r, c=16ct+lc)
  float xr[4][4];
#pragma unroll
  for (int r = 0; r < 4; ++r)
#pragma unroll
    for (int ct = 0; ct < 4; ++ct) {
      const int c = 16 * ct + lc, i = 4 * g + r;
      xr[r][ct] = bf2f(*(const unsigned short*)(
          P + (c >> 5) * 1024 + (((c >> 3) & 3) * 16 + i) * 16 + (c & 7) * 2));
    }

  float uq2[4], uk2[4], uv2[4], pqv[4];
#pragma unroll
  for (int ct = 0; ct < 4; ++ct) {
    const int c = 16 * ct + lc;
    uq2[ct] = 2.f * ws[WS_UQ + c];
    uk2[ct] = 2.f * ws[WS_UK + c];
    uv2[ct] = 2.f * ws[WS_UV + c];
    pqv[ct] = ws[WS_PQ + c];
  }
  const float c0 = ws[WS_SC], sq = ws[WS_SC + 1], sk2 = ws[WS_SC + 2], sv2 = ws[WS_SC + 3];

  const f32x4 z4 = {0.f, 0.f, 0.f, 0.f};
  f32x4 acc[4];
  float nqp[4], nkp[4], nvp[4], pqp[4];

  // ---- Zq = xs@G_q -> |Q| partials
#pragma unroll
  for (int ct = 0; ct < 4; ++ct) acc[ct] = z4;
  product5<1>(wsu, lane, xa0, xa1, acc);
#pragma unroll
  for (int r = 0; r < 4; ++r) {
    float s2 = 0.f;
#pragma unroll
    for (int ct = 0; ct < 4; ++ct) s2 = fmaf(acc[ct][r] + uq2[ct], xr[r][ct], s2);
    nqp[r] = s2;
  }
  // ---- Zk
#pragma unroll
  for (int ct = 0; ct < 4; ++ct) acc[ct] = z4;
  product5<2>(wsu, lane, xa0, xa1, acc);
#pragma unroll
  for (int r = 0; r < 4; ++r) {
    float s2 = 0.f;
#pragma unroll
    for (int ct = 0; ct < 4; ++ct) s2 = fmaf(acc[ct][r] + uk2[ct], xr[r][ct], s2);
    nkp[r] = s2;
  }
  // ---- Zv
#pragma unroll
  for (int ct = 0; ct < 4; ++ct) acc[ct] = z4;
  product5<3>(wsu, lane, xa0, xa1, acc);
#pragma unroll
  for (int r = 0; r < 4; ++r) {
    float s2 = 0.f, p2 = 0.f;
#pragma unroll
    for (int ct = 0; ct < 4; ++ct) {
      s2 = fmaf(acc[ct][r] + uv2[ct], xr[r][ct], s2);
      p2 = fmaf(pqv[ct], xr[r][ct], p2);
    }
    nvp[r] = s2;
    pqp[r] = p2;
  }

  // ---- 16-lane-group reduces via DPP (no DS traffic); norms + row bias
  float invq[4], pqc[4];
#pragma unroll
  for (int r = 0; r < 4; ++r) {
    const float a0 = row_sum16(nqp[r]);
    const float a1 = row_sum16(nkp[r]);
    const float a2 = row_sum16(nvp[r]);
    const float a3 = row_sum16(pqp[r]);
    invq[r] = rsqrtf(a0 + sq);
    pqc[r] = a3 + c0;
    if (lc == 0) {
      nrmW[4 * g + r]      = rsqrtf(a1 + sk2);
      nrmW[16 + 4 * g + r] = rsqrtf(a2 + sv2);
    }
  }

  // ---- T~ = xs@A_qk + pk; restage as bf16 A-frags (overlays xsb, now dead)
  float pkv[4];
#pragma unroll
  for (int ct = 0; ct < 4; ++ct) pkv[ct] = ws[WS_PK + 16 * ct + lc];
#pragma unroll
  for (int ct = 0; ct < 4; ++ct) { f32x4 v = {pkv[ct], pkv[ct], pkv[ct], pkv[ct]}; acc[ct] = v; }
  product5<0>(wsu, lane, xa0, xa1, acc);
#pragma unroll
  for (int r = 0; r < 4; ++r)
#pragma unroll
    for (int ct = 0; ct < 4; ++ct) {
      const int c = 16 * ct + lc, i = 4 * g + r;
      *(unsigned short*)(P + (c >> 5) * 1024 + (((c >> 3) & 3) * 16 + i) * 16 + (c & 7) * 2)
          = f2bf(acc[ct][r]);
    }

  // ---- scores: S = T~ @ xs^T + pqc (B-frag of xs^T == A-frag of xs)
  const short8v ta0 = *(const short8v*)(P + lane * 16);
  const short8v ta1 = *(const short8v*)(P + 1024 + lane * 16);
  f32x4 sv = {pqc[0], pqc[1], pqc[2], pqc[3]};
  sv = mfma16(ta0, xa0, sv);
  sv = mfma16(ta1, xa1, sv);

  // ---- Yv = xs@M_vo + rvo (independent of softmax; overlaps MFMA pipe)
  float rvo[4];
#pragma unroll
  for (int ct = 0; ct < 4; ++ct) rvo[ct] = ws[WS_RVO + 16 * ct + lc];
#pragma unroll
  for (int ct = 0; ct < 4; ++ct) { f32x4 v = {rvo[ct], rvo[ct], rvo[ct], rvo[ct]}; acc[ct] = v; }
  product5<4>(wsu, lane, xa0, xa1, acc);

  // ---- softmax over j (=lc) per row r via DPP, fold 1/|V_j|; stage P A-frags
  const float ikj = nrmW[lc], ivj = nrmW[16 + lc];
  const float sc0 = sv[0] * invq[0] * ikj;
  const float sc1 = sv[1] * invq[1] * ikj;
  const float sc2 = sv[2] * invq[2] * ikj;
  const float sc3 = sv[3] * invq[3] * ikj;
  const float m0 = row_max16(sc0), m1 = row_max16(sc1);
  const float m2 = row_max16(sc2), m3 = row_max16(sc3);
  const float e0 = __expf(sc0 - m0), e1 = __expf(sc1 - m1);
  const float e2 = __expf(sc2 - m2), e3 = __expf(sc3 - m3);
  const float u0 = row_sum16(e0), u1 = row_sum16(e1);
  const float u2 = row_sum16(e2), u3 = row_sum16(e3);
  const float w0 = e0 / u0 * ivj, w1 = e1 / u1 * ivj;
  const float w2 = e2 / u2 * ivj, w3 = e3 / u3 * ivj;
  {
    char* pt = P + PT_OFF + ((lc >> 3) * 16 + 4 * g) * 16 + (lc & 7) * 2;
    *(unsigned short*)(pt)      = f2bf(w0);
    *(unsigned short*)(pt + 16) = f2bf(w1);
    *(unsigned short*)(pt + 32) = f2bf(w2);
    *(unsigned short*)(pt + 48) = f2bf(w3);
  }

  // ---- stage Yv as bf16 B-frags (k = j < 16 -> lanes 0..31 only)
#pragma unroll
  for (int r = 0; r < 4; ++r) {
    const int j = 4 * g + r;
    char* yt = P + YT_OFF + ((j >> 3) * 16 + lc) * 16 + (j & 7) * 2;
#pragma unroll
    for (int ct = 0; ct < 4; ++ct)
      *(unsigned short*)(yt + ct * 512) = f2bf(acc[ct][r]);
  }

  // ---- PV + bias + residual (acc init = bo + resid), D-layout output
  float bov[4];
#pragma unroll
  for (int ct = 0; ct < 4; ++ct) bov[ct] = bo_g[16 * ct + lc];
  short8v pa = {0, 0, 0, 0, 0, 0, 0, 0};
  if (lane < 32) pa = *(const short8v*)(P + PT_OFF + lane * 16);
  f32x4 o[4];
#pragma unroll
  for (int ct = 0; ct < 4; ++ct) {
    f32x4 v = {bov[ct] + xr[0][ct], bov[ct] + xr[1][ct], bov[ct] + xr[2][ct], bov[ct] + xr[3][ct]};
    o[ct] = v;
  }
#pragma unroll
  for (int ct = 0; ct < 4; ++ct) {
    short8v yb = {0, 0, 0, 0, 0, 0, 0, 0};
    if (lane < 32) yb = *(const short8v*)(P + YT_OFF + ct * 512 + lane * 16);
    o[ct] = mfma16(pa, yb, o[ct]);
  }

  // ---- stage final fp32 [16][68] (overlays frag buffers, all dead)
#pragma unroll
  for (int ct = 0; ct < 4; ++ct)
#pragma unroll
    for (int r = 0; r < 4; ++r)
      *(float*)(P + (4 * g + r) * 272 + (16 * ct + lc) * 4) = o[ct][r];

  __syncthreads();
  {  // coalesced flush
    const int px = t & 7, cc = t >> 3;
    float* ob = out + gbase + px;
    const char* rb = lds + px * RPX;
#pragma unroll
    for (int f = 0; f < 16; ++f)
      ob[(size_t)(f * 64 + cc) * 4096] = *(const float*)(rb + f * 272 + cc * 4);
  }
}

extern "C" void kernel_launch(void* const* d_in, const int* in_sizes, int n_in,
                              void* d_out, int out_size, void* d_ws, size_t ws_size,
                              hipStream_t stream) {
  const float* x  = (const float*)d_in[0];
  const float* Wq = (const float*)d_in[1];
  const float* bq = (const float*)d_in[2];
  const float* Wk = (const float*)d_in[3];
  const float* bk = (const float*)d_in[4];
  const float* Wv = (const float*)d_in[5];
  const float* bv = (const float*)d_in[6];
  const float* Wo = (const float*)d_in[7];
  const float* bo = (const float*)d_in[8];
  float* out = (float*)d_out;
  float* ws  = (float*)d_ws;
  (void)in_sizes; (void)n_in; (void)out_size; (void)ws_size;

  k1<<<82, 256, 0, stream>>>(Wq, bq, Wk, bk, Wv, bv, Wo, ws);
  k2_main<<<1024, 512, 0, stream>>>(x, ws, bo, out);
}